// Round 7
// baseline (160.287 us; speedup 1.0000x reference)
//
#include <hip/hip_runtime.h>
#include <hip/hip_bf16.h>

// Problem constants
#define NT      32      // time steps
#define FEAT    128     // in/out features per step
#define TRIB    8       // band width in blocks
#define BATCH   8192
#define INSIZE  (NT*FEAT)   // 4096
#define OUTCOLS (NT*FEAT)   // 4096

typedef __bf16 bf16;
typedef __bf16 bf16x4 __attribute__((ext_vector_type(4)));
typedef __bf16 bf16x8 __attribute__((ext_vector_type(8)));
typedef float  f32x4  __attribute__((ext_vector_type(4)));

__host__ __device__ __forceinline__ int nb_of(int i){ return i < TRIB ? i + 1 : TRIB; }
__host__ __device__ __forceinline__ int lo_of(int i){ int l = i - TRIB + 1; return l > 0 ? l : 0; }
__host__ __device__ __forceinline__ long off_of(int i){
  long sum = (i <= TRIB) ? (long)i*(i+1)/2 : (long)(TRIB*(TRIB+1)/2) + (long)(i - TRIB)*TRIB;
  return sum * (long)(FEAT*FEAT);
}

// ---------------- W conversion (band only, ~15 MB read) ----------------
__global__ void cvt_w_kernel(const float* __restrict__ w, bf16* __restrict__ wp){
  int i = blockIdx.x;
  int n = blockIdx.y;
  int ktl = nb_of(i) * FEAT;
  int lo  = lo_of(i) * FEAT;
  long src = (long)(i*FEAT + n) * INSIZE + lo;
  long dst = off_of(i) + (long)n * ktl;
  for (int e = threadIdx.x * 4; e < ktl; e += blockDim.x * 4){
    f32x4 v = *(const f32x4*)(w + src + e);
    bf16x4 o;
    o.x = (bf16)v.x; o.y = (bf16)v.y; o.z = (bf16)v.z; o.w = (bf16)v.w;
    *(bf16x4*)(wp + dst + e) = o;
  }
}

// ---------------- banded GEMM: 2 blocks/CU, fused x-conversion -------------
// R7: BM=256, BN=128, BK=32. 256 threads = 4 waves (2M x 2N), wave tile
// 128x64 (best LDS-bytes/FLOP of R5) at 72 KiB LDS -> TWO independent
// blocks/CU (R6 proved cross-block overlap saturates LDS).
// A (x, f32) is reg-staged: f32x4 loads issued early in tile t (latency under
// MFMA), converted to bf16 and asm-ds_written (swizzled) after the MFMA
// cluster, 2 tiles ahead. B (wp, bf16) staged via global_load_lds with
// inverse-swizzled source. Single barrier + counted vmcnt per tile.

#define BM 256
#define BN 128
#define BK 32
#define NSTAGE 3
#define A_ELEMS (BM*BK)              // 8192 elems = 16 KiB
#define B_ELEMS (BN*BK)              // 4096 elems =  8 KiB
#define TILE_ELEMS (A_ELEMS + B_ELEMS)

__device__ __forceinline__ void gload16(const void* g, void* l){
  __builtin_amdgcn_global_load_lds(
      (__attribute__((address_space(1))) unsigned int*)(unsigned long long)g,
      (__attribute__((address_space(3))) unsigned int*)l,
      16, 0, 0);
}

__device__ __forceinline__ unsigned lds_addr(void* p){
  return (unsigned)(unsigned long long)(__attribute__((address_space(3))) void*)p;
}

__device__ __forceinline__ bf16x8 ds_read16(unsigned addr){
  bf16x8 r;
  asm volatile("ds_read_b128 %0, %1" : "=&v"(r) : "v"(addr));
  return r;
}

__device__ __forceinline__ void ds_write16(unsigned addr, bf16x8 v){
  asm volatile("ds_write_b128 %0, %1" :: "v"(addr), "v"(v) : "memory");
}

__global__ __launch_bounds__(256, 2)
void gemm_band_kernel(const float* __restrict__ x, const bf16* __restrict__ wp,
                      const float* __restrict__ bias, float* __restrict__ out){
  __shared__ __align__(16) bf16 lds[NSTAGE * TILE_ELEMS];   // 72 KiB

  const int bid = blockIdx.x;
  const int mt  = bid & 31;            // fast dim: m-tile (L2/L3 locality)
  const int i   = 31 - (bid >> 5);     // slow dim, descending (LPT)
  const int m0  = mt * BM;
  const int nbK = nb_of(i);
  const int ntiles = nbK * (FEAT / BK);    // 4..32
  const int lo  = lo_of(i) * FEAT;
  const int Kt  = nbK * FEAT;
  const long wpo = off_of(i);

  const int tid  = threadIdx.x;
  const int lane = tid & 63;
  const int wid  = tid >> 6;           // 0..3
  const int wr   = wid >> 1;           // 0..1 -> 128-row M strip
  const int wc   = wid & 1;            // 0..1 -> 64-col N strip
  const int fr   = lane & 15;
  const int ks   = lane >> 4;          // 0..3 k-slot (8 bf16)

  const unsigned ldsBase = lds_addr((void*)lds);

  // -------- loop-invariant LDS read BYTE offsets (stage-relative) ----------
  unsigned offA[8], offB[4];
  #pragma unroll
  for (int mi = 0; mi < 8; ++mi){
    const int row = wr*128 + mi*16 + fr;
    const int u = row >> 1;
    const int q = (((row & 1) << 2) | ks) ^ (u & 7);
    offA[mi] = (unsigned)(u*128 + q*16);
  }
  #pragma unroll
  for (int ni = 0; ni < 4; ++ni){
    const int row = wc*64 + ni*16 + fr;
    const int u = row >> 1;
    const int q = (((row & 1) << 2) | ks) ^ (u & 7);
    offB[ni] = (unsigned)(A_ELEMS*2 + u*128 + q*16);
  }

  // -------- B staging: inverse-swizzled global source, linear LDS dest -----
  const bf16* srcB[2];
  int dstB[2];
  #pragma unroll
  for (int j = 0; j < 2; ++j){
    const int c = j*256 + tid;           // 16B chunk index, 512 total
    const int u = c >> 3, qq = c & 7;
    const int s8 = qq ^ (u & 7);
    const int r  = 2*u + (s8 >> 2);
    const int sb = s8 & 3;
    srcB[j] = wp + wpo + (long)r * Kt + sb*8;
    dstB[j] = A_ELEMS + (j*256 + wid*64) * 8;   // wave-uniform (+lane*16B by HW)
  }
  auto stageB = [&](bf16* base, int t){
    gload16(srcB[0] + t*BK, base + dstB[0]);
    gload16(srcB[1] + t*BK, base + dstB[1]);
  };

  // -------- A reg-staging: thread owns rows {ar, ar+128}, k-half ah --------
  const int ar = tid >> 1;             // 0..127
  const int ah = tid & 1;              // 0/1 -> k cols [16h, 16h+16)
  const float* ax0 = x + (long)(m0 + ar)       * INSIZE + lo + ah*16;
  const float* ax1 = x + (long)(m0 + ar + 128) * INSIZE + lo + ah*16;

  f32x4 av[8];
  auto loadA = [&](int t){
    const float* p0 = ax0 + t*BK;
    const float* p1 = ax1 + t*BK;
    #pragma unroll
    for (int j = 0; j < 4; ++j) av[j]     = *(const f32x4*)(p0 + j*4);
    #pragma unroll
    for (int j = 0; j < 4; ++j) av[4 + j] = *(const f32x4*)(p1 + j*4);
  };
  auto writeA = [&](int stg){
    const unsigned base = ldsBase + (unsigned)stg * (TILE_ELEMS*2);
    #pragma unroll
    for (int rs = 0; rs < 2; ++rs){
      const int row = ar + rs*128;
      const int u = row >> 1;
      #pragma unroll
      for (int s2 = 0; s2 < 2; ++s2){
        const int s = ah*2 + s2;
        const int q = (((row & 1) << 2) | s) ^ (u & 7);
        const f32x4 v0 = av[rs*4 + s2*2];
        const f32x4 v1 = av[rs*4 + s2*2 + 1];
        bf16x8 o;
        o[0]=(bf16)v0.x; o[1]=(bf16)v0.y; o[2]=(bf16)v0.z; o[3]=(bf16)v0.w;
        o[4]=(bf16)v1.x; o[5]=(bf16)v1.y; o[6]=(bf16)v1.z; o[7]=(bf16)v1.w;
        ds_write16(base + (unsigned)(u*128 + q*16), o);
      }
    }
  };

  // -------- prologue: fill stages 0,1 (ntiles >= 4 always) -----------------
  loadA(0); stageB(lds, 0);
  writeA(0);                                    // compiler auto-waits A(0)
  loadA(1); stageB(lds + TILE_ELEMS, 1);
  writeA(1);                                    // auto-wait A(1) retires B(0)
  asm volatile("s_waitcnt lgkmcnt(0)" ::: "memory");
  __builtin_amdgcn_s_barrier();
  asm volatile("" ::: "memory");

  f32x4 acc[8][4] = {};

  int stC = 0, stPf = 2;
  for (int t = 0; t < ntiles; ++t){
    const unsigned cA = ldsBase + (unsigned)stC * (TILE_ELEMS*2);
    const bool pf = (t + 2 < ntiles);

    // ---- issue 12 asm ds_reads for tile t
    bf16x8 a0 = ds_read16(cA + offA[0]);
    bf16x8 a1 = ds_read16(cA + offA[1]);
    bf16x8 a2 = ds_read16(cA + offA[2]);
    bf16x8 a3 = ds_read16(cA + offA[3]);
    bf16x8 a4 = ds_read16(cA + offA[4]);
    bf16x8 a5 = ds_read16(cA + offA[5]);
    bf16x8 a6 = ds_read16(cA + offA[6]);
    bf16x8 a7 = ds_read16(cA + offA[7]);
    bf16x8 b0 = ds_read16(cA + offB[0]);
    bf16x8 b1 = ds_read16(cA + offB[1]);
    bf16x8 b2 = ds_read16(cA + offB[2]);
    bf16x8 b3 = ds_read16(cA + offB[3]);

    // ---- issue tile t+2 staging: A f32 loads to regs + B DMA (buf t-1)
    if (pf){ loadA(t + 2); stageB(lds + stPf * TILE_ELEMS, t + 2); }

    // ---- my ds_reads done -> MFMA cluster (free-run, no barrier)
    asm volatile("s_waitcnt lgkmcnt(0)" ::: "memory");
    __builtin_amdgcn_sched_barrier(0);
    __builtin_amdgcn_s_setprio(1);
    acc[0][0] = __builtin_amdgcn_mfma_f32_16x16x32_bf16(a0, b0, acc[0][0], 0,0,0);
    acc[0][1] = __builtin_amdgcn_mfma_f32_16x16x32_bf16(a0, b1, acc[0][1], 0,0,0);
    acc[0][2] = __builtin_amdgcn_mfma_f32_16x16x32_bf16(a0, b2, acc[0][2], 0,0,0);
    acc[0][3] = __builtin_amdgcn_mfma_f32_16x16x32_bf16(a0, b3, acc[0][3], 0,0,0);
    acc[1][0] = __builtin_amdgcn_mfma_f32_16x16x32_bf16(a1, b0, acc[1][0], 0,0,0);
    acc[1][1] = __builtin_amdgcn_mfma_f32_16x16x32_bf16(a1, b1, acc[1][1], 0,0,0);
    acc[1][2] = __builtin_amdgcn_mfma_f32_16x16x32_bf16(a1, b2, acc[1][2], 0,0,0);
    acc[1][3] = __builtin_amdgcn_mfma_f32_16x16x32_bf16(a1, b3, acc[1][3], 0,0,0);
    acc[2][0] = __builtin_amdgcn_mfma_f32_16x16x32_bf16(a2, b0, acc[2][0], 0,0,0);
    acc[2][1] = __builtin_amdgcn_mfma_f32_16x16x32_bf16(a2, b1, acc[2][1], 0,0,0);
    acc[2][2] = __builtin_amdgcn_mfma_f32_16x16x32_bf16(a2, b2, acc[2][2], 0,0,0);
    acc[2][3] = __builtin_amdgcn_mfma_f32_16x16x32_bf16(a2, b3, acc[2][3], 0,0,0);
    acc[3][0] = __builtin_amdgcn_mfma_f32_16x16x32_bf16(a3, b0, acc[3][0], 0,0,0);
    acc[3][1] = __builtin_amdgcn_mfma_f32_16x16x32_bf16(a3, b1, acc[3][1], 0,0,0);
    acc[3][2] = __builtin_amdgcn_mfma_f32_16x16x32_bf16(a3, b2, acc[3][2], 0,0,0);
    acc[3][3] = __builtin_amdgcn_mfma_f32_16x16x32_bf16(a3, b3, acc[3][3], 0,0,0);
    acc[4][0] = __builtin_amdgcn_mfma_f32_16x16x32_bf16(a4, b0, acc[4][0], 0,0,0);
    acc[4][1] = __builtin_amdgcn_mfma_f32_16x16x32_bf16(a4, b1, acc[4][1], 0,0,0);
    acc[4][2] = __builtin_amdgcn_mfma_f32_16x16x32_bf16(a4, b2, acc[4][2], 0,0,0);
    acc[4][3] = __builtin_amdgcn_mfma_f32_16x16x32_bf16(a4, b3, acc[4][3], 0,0,0);
    acc[5][0] = __builtin_amdgcn_mfma_f32_16x16x32_bf16(a5, b0, acc[5][0], 0,0,0);
    acc[5][1] = __builtin_amdgcn_mfma_f32_16x16x32_bf16(a5, b1, acc[5][1], 0,0,0);
    acc[5][2] = __builtin_amdgcn_mfma_f32_16x16x32_bf16(a5, b2, acc[5][2], 0,0,0);
    acc[5][3] = __builtin_amdgcn_mfma_f32_16x16x32_bf16(a5, b3, acc[5][3], 0,0,0);
    acc[6][0] = __builtin_amdgcn_mfma_f32_16x16x32_bf16(a6, b0, acc[6][0], 0,0,0);
    acc[6][1] = __builtin_amdgcn_mfma_f32_16x16x32_bf16(a6, b1, acc[6][1], 0,0,0);
    acc[6][2] = __builtin_amdgcn_mfma_f32_16x16x32_bf16(a6, b2, acc[6][2], 0,0,0);
    acc[6][3] = __builtin_amdgcn_mfma_f32_16x16x32_bf16(a6, b3, acc[6][3], 0,0,0);
    acc[7][0] = __builtin_amdgcn_mfma_f32_16x16x32_bf16(a7, b0, acc[7][0], 0,0,0);
    acc[7][1] = __builtin_amdgcn_mfma_f32_16x16x32_bf16(a7, b1, acc[7][1], 0,0,0);
    acc[7][2] = __builtin_amdgcn_mfma_f32_16x16x32_bf16(a7, b2, acc[7][2], 0,0,0);
    acc[7][3] = __builtin_amdgcn_mfma_f32_16x16x32_bf16(a7, b3, acc[7][3], 0,0,0);
    __builtin_amdgcn_s_setprio(0);
    asm volatile("" ::: "memory");

    // ---- convert + ds_write A(t+2) (loads auto-waited by compiler)
    if (pf) writeA(stPf);

    // ---- single per-tile sync: B(t+1) retired (vmcnt), A-writes visible
    if (t + 1 < ntiles){
      if (pf) asm volatile("s_waitcnt vmcnt(2) lgkmcnt(0)" ::: "memory");
      else    asm volatile("s_waitcnt vmcnt(0) lgkmcnt(0)" ::: "memory");
      __builtin_amdgcn_s_barrier();
      asm volatile("" ::: "memory");
    }

    stC  = (stC  == NSTAGE-1) ? 0 : stC  + 1;
    stPf = (stPf == NSTAGE-1) ? 0 : stPf + 1;
  }

  // -------- epilogue: C/D layout col = lane&15, row = (lane>>4)*4 + reg ----
  #pragma unroll
  for (int ni = 0; ni < 4; ++ni){
    const int gcol = i*FEAT + wc*64 + ni*16 + fr;
    const float bv = bias[gcol];
    #pragma unroll
    for (int mi = 0; mi < 8; ++mi){
      const int rbase = m0 + wr*128 + mi*16 + ks*4;
      #pragma unroll
      for (int r2 = 0; r2 < 4; ++r2)
        out[(long)(rbase + r2) * OUTCOLS + gcol] = acc[mi][ni][r2] + bv;
    }
  }
}

// ---------------- fallback (tiny ws): naive fp32, band-limited ----------------
__global__ void naive_kernel(const float* __restrict__ x, const float* __restrict__ w,
                             const float* __restrict__ bias, float* __restrict__ out){
  long idx = (long)blockIdx.x * blockDim.x + threadIdx.x;
  int o = (int)(idx & (OUTCOLS - 1));
  int b = (int)(idx >> 12);
  int i = o >> 7;
  int lo = lo_of(i) * FEAT, hi = (i + 1) * FEAT;
  const float* xr = x + (long)b * INSIZE;
  const float* wr = w + (long)o * INSIZE;
  float s = bias[o];
  for (int k = lo; k < hi; k += 4){
    f32x4 xv = *(const f32x4*)(xr + k);
    f32x4 wv = *(const f32x4*)(wr + k);
    s += xv.x*wv.x + xv.y*wv.y + xv.z*wv.z + xv.w*wv.w;
  }
  out[idx] = s;
}

// ---------------- launch ----------------
extern "C" void kernel_launch(void* const* d_in, const int* in_sizes, int n_in,
                              void* d_out, int out_size, void* d_ws, size_t ws_size,
                              hipStream_t stream) {
  const float* x    = (const float*)d_in[0];
  const float* w    = (const float*)d_in[1];
  const float* bias = (const float*)d_in[2];
  float* out = (float*)d_out;

  const size_t w_bytes = (size_t)228 * FEAT * FEAT * sizeof(bf16);     // ~7.5 MiB
  if (ws_size >= w_bytes){
    bf16* wp = (bf16*)d_ws;
    cvt_w_kernel<<<dim3(NT, FEAT), 256, 0, stream>>>(w, wp);
    gemm_band_kernel<<<dim3(NT * (BATCH/BM)), 256, 0, stream>>>(x, wp, bias, out);
  } else {
    naive_kernel<<<(long)BATCH * OUTCOLS / 256, 256, 0, stream>>>(x, w, bias, out);
  }
}

// Round 8
// 134.487 us; speedup vs baseline: 1.1918x; 1.1918x over previous
//
#include <hip/hip_runtime.h>
#include <hip/hip_bf16.h>

// Problem constants
#define NT      32      // time steps
#define FEAT    128     // in/out features per step
#define TRIB    8       // band width in blocks
#define BATCH   8192
#define INSIZE  (NT*FEAT)   // 4096
#define OUTCOLS (NT*FEAT)   // 4096

typedef __bf16 bf16;
typedef __bf16 bf16x4 __attribute__((ext_vector_type(4)));
typedef __bf16 bf16x8 __attribute__((ext_vector_type(8)));
typedef float  f32x4  __attribute__((ext_vector_type(4)));

__host__ __device__ __forceinline__ int nb_of(int i){ return i < TRIB ? i + 1 : TRIB; }
__host__ __device__ __forceinline__ int lo_of(int i){ int l = i - TRIB + 1; return l > 0 ? l : 0; }
__host__ __device__ __forceinline__ long off_of(int i){
  long sum = (i <= TRIB) ? (long)i*(i+1)/2 : (long)(TRIB*(TRIB+1)/2) + (long)(i - TRIB)*TRIB;
  return sum * (long)(FEAT*FEAT);
}

// ---------------- conversion kernels ----------------

__global__ void cvt_x_kernel(const float* __restrict__ x, bf16* __restrict__ xb, long n4){
  long idx = (long)blockIdx.x * blockDim.x + threadIdx.x;
  long stride = (long)gridDim.x * blockDim.x;
  const f32x4* src = (const f32x4*)x;
  bf16x4* dst = (bf16x4*)xb;
  for (long i = idx; i < n4; i += stride){
    f32x4 v = src[i];
    bf16x4 o;
    o.x = (bf16)v.x; o.y = (bf16)v.y; o.z = (bf16)v.z; o.w = (bf16)v.w;
    dst[i] = o;
  }
}

__global__ void cvt_w_kernel(const float* __restrict__ w, bf16* __restrict__ wp){
  int i = blockIdx.x;
  int n = blockIdx.y;
  int ktl = nb_of(i) * FEAT;
  int lo  = lo_of(i) * FEAT;
  long src = (long)(i*FEAT + n) * INSIZE + lo;
  long dst = off_of(i) + (long)n * ktl;
  for (int e = threadIdx.x * 4; e < ktl; e += blockDim.x * 4){
    f32x4 v = *(const f32x4*)(w + src + e);
    bf16x4 o;
    o.x = (bf16)v.x; o.y = (bf16)v.y; o.z = (bf16)v.z; o.w = (bf16)v.w;
    *(bf16x4*)(wp + dst + e) = o;
  }
}

// ------------- banded GEMM: m201-style 4-phase-per-K64 pipeline -------------
// BM=512, BN=128, BK=64. 512 threads = 8 waves (4M x 2N), wave tile 128x64.
// 2-stage LDS double buffer = (512+128)*64*2B*2 = 160 KiB exactly.
// Per K64-tile: 4 phases, each {ds_reads (4-8 b128) | stage slice (2-3
// gload_lds) -> barrier -> lgkmcnt(0) -> sched_barrier -> setprio(1) ->
// 16 MFMA -> setprio(0) -> barrier}. vmcnt(0) once per tile at P3 (next
// tile's 10 loads were issued ~3 phases earlier -> drain nearly free).
// XOR swizzle: rows are 128 B (8 x 16B slots); slot q = s ^ (fr&7) applied on
// the pre-permuted GLOBAL source (linear LDS dest for global_load_lds) and
// on ds_read addresses. Conflict-free (R3-R6: SQ_LDS_BANK_CONFLICT = 0).

#define BM 512
#define BN 128
#define BK 64
#define A_ELEMS (BM*BK)              // 32768 elems = 64 KiB
#define B_ELEMS (BN*BK)              // 8192 elems = 16 KiB
#define TILE_ELEMS (A_ELEMS + B_ELEMS)   // 40960 elems = 80 KiB/stage

__device__ __forceinline__ void gload16(const void* g, void* l){
  __builtin_amdgcn_global_load_lds(
      (__attribute__((address_space(1))) unsigned int*)(unsigned long long)g,
      (__attribute__((address_space(3))) unsigned int*)l,
      16, 0, 0);
}

__device__ __forceinline__ unsigned lds_addr(void* p){
  return (unsigned)(unsigned long long)(__attribute__((address_space(3))) void*)p;
}

__device__ __forceinline__ bf16x8 ds_read16(unsigned addr){
  bf16x8 r;
  asm volatile("ds_read_b128 %0, %1" : "=&v"(r) : "v"(addr));
  return r;
}

#define MFMA16(AARR, BB0, BB1, BB2, BB3, MBASE)                                      \
  acc[MBASE+0][0] = __builtin_amdgcn_mfma_f32_16x16x32_bf16(AARR[0], BB0, acc[MBASE+0][0],0,0,0); \
  acc[MBASE+0][1] = __builtin_amdgcn_mfma_f32_16x16x32_bf16(AARR[0], BB1, acc[MBASE+0][1],0,0,0); \
  acc[MBASE+0][2] = __builtin_amdgcn_mfma_f32_16x16x32_bf16(AARR[0], BB2, acc[MBASE+0][2],0,0,0); \
  acc[MBASE+0][3] = __builtin_amdgcn_mfma_f32_16x16x32_bf16(AARR[0], BB3, acc[MBASE+0][3],0,0,0); \
  acc[MBASE+1][0] = __builtin_amdgcn_mfma_f32_16x16x32_bf16(AARR[1], BB0, acc[MBASE+1][0],0,0,0); \
  acc[MBASE+1][1] = __builtin_amdgcn_mfma_f32_16x16x32_bf16(AARR[1], BB1, acc[MBASE+1][1],0,0,0); \
  acc[MBASE+1][2] = __builtin_amdgcn_mfma_f32_16x16x32_bf16(AARR[1], BB2, acc[MBASE+1][2],0,0,0); \
  acc[MBASE+1][3] = __builtin_amdgcn_mfma_f32_16x16x32_bf16(AARR[1], BB3, acc[MBASE+1][3],0,0,0); \
  acc[MBASE+2][0] = __builtin_amdgcn_mfma_f32_16x16x32_bf16(AARR[2], BB0, acc[MBASE+2][0],0,0,0); \
  acc[MBASE+2][1] = __builtin_amdgcn_mfma_f32_16x16x32_bf16(AARR[2], BB1, acc[MBASE+2][1],0,0,0); \
  acc[MBASE+2][2] = __builtin_amdgcn_mfma_f32_16x16x32_bf16(AARR[2], BB2, acc[MBASE+2][2],0,0,0); \
  acc[MBASE+2][3] = __builtin_amdgcn_mfma_f32_16x16x32_bf16(AARR[2], BB3, acc[MBASE+2][3],0,0,0); \
  acc[MBASE+3][0] = __builtin_amdgcn_mfma_f32_16x16x32_bf16(AARR[3], BB0, acc[MBASE+3][0],0,0,0); \
  acc[MBASE+3][1] = __builtin_amdgcn_mfma_f32_16x16x32_bf16(AARR[3], BB1, acc[MBASE+3][1],0,0,0); \
  acc[MBASE+3][2] = __builtin_amdgcn_mfma_f32_16x16x32_bf16(AARR[3], BB2, acc[MBASE+3][2],0,0,0); \
  acc[MBASE+3][3] = __builtin_amdgcn_mfma_f32_16x16x32_bf16(AARR[3], BB3, acc[MBASE+3][3],0,0,0);

#define PHASE_PRE  __builtin_amdgcn_s_barrier();                                  \
                   asm volatile("s_waitcnt lgkmcnt(0)" ::: "memory");             \
                   __builtin_amdgcn_sched_barrier(0);                             \
                   __builtin_amdgcn_s_setprio(1);
#define PHASE_POST __builtin_amdgcn_s_setprio(0);                                 \
                   __builtin_amdgcn_s_barrier();                                  \
                   asm volatile("" ::: "memory");

__global__ __launch_bounds__(512, 2)
void gemm_band_kernel(const bf16* __restrict__ xb, const bf16* __restrict__ wp,
                      const float* __restrict__ bias, float* __restrict__ out){
  __shared__ __align__(16) bf16 lds[2 * TILE_ELEMS];   // 160 KiB exactly

  const int bid = blockIdx.x;
  const int mt  = bid & 15;            // fast dim: m-tile (L2/L3 locality)
  const int i   = 31 - (bid >> 4);     // slow dim, descending (LPT)
  const int m0  = mt * BM;
  const int nbK = nb_of(i);
  const int ntiles = nbK * (FEAT / BK);    // 2..16 K64-tiles
  const int lo  = lo_of(i) * FEAT;
  const int Kt  = nbK * FEAT;
  const long wpo = off_of(i);

  const int tid  = threadIdx.x;
  const int lane = tid & 63;
  const int wid  = tid >> 6;           // 0..7
  const int wr   = wid >> 1;           // 0..3 -> 128-row M strip
  const int wc   = wid & 1;            // 0..1 -> 64-col N strip
  const int fr   = lane & 15;
  const int ks   = lane >> 4;          // 0..3 k-slot (8 bf16)

  const unsigned ldsBase = lds_addr((void*)lds);

  // -------- loop-invariant LDS read BYTE offsets (stage-relative) ----------
  // row = 128 B = 8 x 16B slots; fragment (kh,ks) at slot q=(kh*4+ks)^(fr&7)
  const unsigned q0 = (unsigned)(ks ^ (fr & 7));
  unsigned offA0[8], offA1[8], offB0[4], offB1[4];
  #pragma unroll
  for (int mi = 0; mi < 8; ++mi){
    const unsigned rb = (unsigned)(wr*128 + mi*16 + fr) * 128u;
    offA0[mi] = rb + q0*16u;
    offA1[mi] = rb + (q0^4u)*16u;
  }
  #pragma unroll
  for (int ni = 0; ni < 4; ++ni){
    const unsigned rb = (unsigned)(A_ELEMS*2) + (unsigned)(wc*64 + ni*16 + fr) * 128u;
    offB0[ni] = rb + q0*16u;
    offB1[ni] = rb + (q0^4u)*16u;
  }

  // -------- staging: pre-swizzled global source, linear LDS dest -----------
  // chunk d: row r=d>>3, slot s=d&7 -> global k-slot (s^(r&7)). For
  // d=j*512+tid: r&7=(tid>>3)&7, s=tid&7 -> sa uniform over j.
  const int sa = (tid & 7) ^ ((tid >> 3) & 7);
  const bf16* srcA[8];
  int dstA[8];
  #pragma unroll
  for (int j = 0; j < 8; ++j){
    const int r = j*64 + (tid >> 3);           // 0..511
    srcA[j] = xb + (long)(m0 + r) * INSIZE + lo + sa*8;
    dstA[j] = (j*512 + wid*64) * 8;            // wave-uniform (+lane*16B by HW)
  }
  const bf16* srcB[2];
  int dstB[2];
  #pragma unroll
  for (int j = 0; j < 2; ++j){
    const int r = j*64 + (tid >> 3);           // 0..127
    srcB[j] = wp + wpo + (long)r * Kt + sa*8;
    dstB[j] = A_ELEMS + (j*512 + wid*64) * 8;
  }

  // -------- prologue: stage tile 0 into buf 0 ------------------------------
  {
    bf16* b0 = lds;
    #pragma unroll
    for (int j = 0; j < 8; ++j) gload16(srcA[j], b0 + dstA[j]);
    gload16(srcB[0], b0 + dstB[0]);
    gload16(srcB[1], b0 + dstB[1]);
  }
  f32x4 acc[8][4] = {};
  asm volatile("s_waitcnt vmcnt(0)" ::: "memory");
  __builtin_amdgcn_s_barrier();
  asm volatile("" ::: "memory");

  for (int t = 0; t < ntiles; ++t){
    const unsigned cA = ldsBase + (unsigned)(t & 1) * (TILE_ELEMS*2);
    bf16* pb = lds + ((t & 1) ^ 1) * TILE_ELEMS;
    const bool pf = (t + 1 < ntiles);
    const int tn = t + 1;

    bf16x8 a[4], b0, b1, b2, b3;

    // ---- P0: a[0-3] k0 + b[0-3] k0 (8 reads); stage A0,A1,B0
    a[0] = ds_read16(cA + offA0[0]);
    a[1] = ds_read16(cA + offA0[1]);
    a[2] = ds_read16(cA + offA0[2]);
    a[3] = ds_read16(cA + offA0[3]);
    b0 = ds_read16(cA + offB0[0]);
    b1 = ds_read16(cA + offB0[1]);
    b2 = ds_read16(cA + offB0[2]);
    b3 = ds_read16(cA + offB0[3]);
    if (pf){
      gload16(srcA[0] + tn*BK, pb + dstA[0]);
      gload16(srcA[1] + tn*BK, pb + dstA[1]);
      gload16(srcB[0] + tn*BK, pb + dstB[0]);
    }
    PHASE_PRE
    MFMA16(a, b0, b1, b2, b3, 0)
    PHASE_POST

    // ---- P1: a[4-7] k0 (4 reads); stage A2,A3
    a[0] = ds_read16(cA + offA0[4]);
    a[1] = ds_read16(cA + offA0[5]);
    a[2] = ds_read16(cA + offA0[6]);
    a[3] = ds_read16(cA + offA0[7]);
    if (pf){
      gload16(srcA[2] + tn*BK, pb + dstA[2]);
      gload16(srcA[3] + tn*BK, pb + dstA[3]);
    }
    PHASE_PRE
    MFMA16(a, b0, b1, b2, b3, 4)
    PHASE_POST

    // ---- P2: a[0-3] k1 + b[0-3] k1 (8 reads); stage A4,A5,B1
    a[0] = ds_read16(cA + offA1[0]);
    a[1] = ds_read16(cA + offA1[1]);
    a[2] = ds_read16(cA + offA1[2]);
    a[3] = ds_read16(cA + offA1[3]);
    b0 = ds_read16(cA + offB1[0]);
    b1 = ds_read16(cA + offB1[1]);
    b2 = ds_read16(cA + offB1[2]);
    b3 = ds_read16(cA + offB1[3]);
    if (pf){
      gload16(srcA[4] + tn*BK, pb + dstA[4]);
      gload16(srcA[5] + tn*BK, pb + dstA[5]);
      gload16(srcB[1] + tn*BK, pb + dstB[1]);
    }
    PHASE_PRE
    MFMA16(a, b0, b1, b2, b3, 0)
    PHASE_POST

    // ---- P3: a[4-7] k1 (4 reads); stage A6,A7; vmcnt once per tile
    a[0] = ds_read16(cA + offA1[4]);
    a[1] = ds_read16(cA + offA1[5]);
    a[2] = ds_read16(cA + offA1[6]);
    a[3] = ds_read16(cA + offA1[7]);
    if (pf){
      gload16(srcA[6] + tn*BK, pb + dstA[6]);
      gload16(srcA[7] + tn*BK, pb + dstA[7]);
    }
    PHASE_PRE
    MFMA16(a, b0, b1, b2, b3, 4)
    __builtin_amdgcn_s_setprio(0);
    if (pf) asm volatile("s_waitcnt vmcnt(0)" ::: "memory");  // t+1 landed (issued ~3 phases ago)
    __builtin_amdgcn_s_barrier();
    asm volatile("" ::: "memory");
  }

  // -------- epilogue: C/D layout col = lane&15, row = (lane>>4)*4 + reg ----
  #pragma unroll
  for (int ni = 0; ni < 4; ++ni){
    const int gcol = i*FEAT + wc*64 + ni*16 + fr;
    const float bv = bias[gcol];
    #pragma unroll
    for (int mi = 0; mi < 8; ++mi){
      const int rbase = m0 + wr*128 + mi*16 + ks*4;
      #pragma unroll
      for (int r2 = 0; r2 < 4; ++r2)
        out[(long)(rbase + r2) * OUTCOLS + gcol] = acc[mi][ni][r2] + bv;
    }
  }
}

// ---------------- fallback (tiny ws): naive fp32, band-limited ----------------
__global__ void naive_kernel(const float* __restrict__ x, const float* __restrict__ w,
                             const float* __restrict__ bias, float* __restrict__ out){
  long idx = (long)blockIdx.x * blockDim.x + threadIdx.x;
  int o = (int)(idx & (OUTCOLS - 1));
  int b = (int)(idx >> 12);
  int i = o >> 7;
  int lo = lo_of(i) * FEAT, hi = (i + 1) * FEAT;
  const float* xr = x + (long)b * INSIZE;
  const float* wr = w + (long)o * INSIZE;
  float s = bias[o];
  for (int k = lo; k < hi; k += 4){
    f32x4 xv = *(const f32x4*)(xr + k);
    f32x4 wv = *(const f32x4*)(wr + k);
    s += xv.x*wv.x + xv.y*wv.y + xv.z*wv.z + xv.w*wv.w;
  }
  out[idx] = s;
}

// ---------------- launch ----------------
extern "C" void kernel_launch(void* const* d_in, const int* in_sizes, int n_in,
                              void* d_out, int out_size, void* d_ws, size_t ws_size,
                              hipStream_t stream) {
  const float* x    = (const float*)d_in[0];
  const float* w    = (const float*)d_in[1];
  const float* bias = (const float*)d_in[2];
  float* out = (float*)d_out;

  const size_t x_bytes = (size_t)BATCH * INSIZE * sizeof(bf16);        // 64 MiB
  const size_t w_bytes = (size_t)228 * FEAT * FEAT * sizeof(bf16);     // ~7.5 MiB
  if (ws_size >= x_bytes + w_bytes){
    bf16* xb = (bf16*)d_ws;
    bf16* wp = (bf16*)((char*)d_ws + x_bytes);
    cvt_x_kernel<<<2048, 256, 0, stream>>>(x, xb, (long)BATCH * INSIZE / 4);
    cvt_w_kernel<<<dim3(NT, FEAT), 256, 0, stream>>>(w, wp);
    gemm_band_kernel<<<dim3(NT * (BATCH/BM)), 512, 0, stream>>>(xb, wp, bias, out);
  } else {
    naive_kernel<<<(long)BATCH * OUTCOLS / 256, 256, 0, stream>>>(x, w, bias, out);
  }
}